// Round 2
// baseline (1223.339 us; speedup 1.0000x reference)
//
#include <hip/hip_runtime.h>
#include <stdint.h>

// Problem dims (fixed by harness)
#define DDIM 1024
#define LSEQ 2048
#define BSZ  8
#define FDIM 4096
#define MROWS (BSZ*LSEQ)   // 16384

typedef float        f32x4  __attribute__((ext_vector_type(4)));
typedef unsigned int u32x4  __attribute__((ext_vector_type(4)));

using gas_void = const __attribute__((address_space(1))) void;
using las_void = __attribute__((address_space(3))) void;

__device__ __forceinline__ void gload16(const void* g, void* l) {
    // async global->LDS, 16B per lane; LDS dest = wave-uniform base + lane*16
    __builtin_amdgcn_global_load_lds((gas_void*)g, (las_void*)l, 16, 0, 0);
}

__device__ __forceinline__ void mfma_bf16(f32x4& d, u32x4 a, u32x4 b) {
    // v_mfma_f32_16x16x32_bf16: A,B = 8 bf16 (4 VGPR) each, C/D = 4 f32
    asm("v_mfma_f32_16x16x32_bf16 %0, %1, %2, %0" : "+v"(d) : "v"(a), "v"(b));
}

__device__ __forceinline__ unsigned short f2bf(float f) {
    __bf16 h = (__bf16)f;
    return __builtin_bit_cast(unsigned short, h);
}

// ---------------- weight fp32 -> bf16 ----------------
__global__ __launch_bounds__(256) void cvt_bf16(const float* __restrict__ src,
                                                __bf16* __restrict__ dst, int n4)
{
    int i = blockIdx.x * 256 + threadIdx.x;
    if (i >= n4) return;
    float4 f = ((const float4*)src)[i];
    ushort4 o;
    o.x = f2bf(f.x); o.y = f2bf(f.y); o.z = f2bf(f.z); o.w = f2bf(f.w);
    ((ushort4*)dst)[i] = o;
}

// ---------------- block reduce (4 scalars over 256 threads) ----------------
__device__ __forceinline__ void blk_reduce4(float& a, float& b, float& c, float& d) {
#pragma unroll
    for (int off = 32; off >= 1; off >>= 1) {
        a += __shfl_xor(a, off, 64);
        b += __shfl_xor(b, off, 64);
        c += __shfl_xor(c, off, 64);
        d += __shfl_xor(d, off, 64);
    }
    __shared__ float sm[4][4];
    const int tid = threadIdx.x;
    if ((tid & 63) == 0) {
        sm[tid >> 6][0] = a; sm[tid >> 6][1] = b;
        sm[tid >> 6][2] = c; sm[tid >> 6][3] = d;
    }
    __syncthreads();
    a = sm[0][0] + sm[1][0] + sm[2][0] + sm[3][0];
    b = sm[0][1] + sm[1][1] + sm[2][1] + sm[3][1];
    c = sm[0][2] + sm[1][2] + sm[2][2] + sm[3][2];
    d = sm[0][3] + sm[1][3] + sm[2][3] + sm[3][3];
}

// ---------------- LN + time_shift + mix (attention: 3 outputs) ----------------
__global__ __launch_bounds__(256) void ln_mix3(
    const float* __restrict__ xin, const float* __restrict__ lnw, const float* __restrict__ lnb,
    const float* __restrict__ mkv, const float* __restrict__ mvv, const float* __restrict__ mrv,
    __bf16* __restrict__ ok, __bf16* __restrict__ ov, __bf16* __restrict__ orr)
{
    const int row = blockIdx.x;          // b*L + l
    const int l   = row & (LSEQ - 1);
    const int tid = threadIdx.x;
    const size_t rbase = (size_t)row * DDIM;
    const float4 cur = ((const float4*)(xin + rbase))[tid];
    float4 prv = make_float4(0.f, 0.f, 0.f, 0.f);
    if (l > 0) prv = ((const float4*)(xin + rbase - DDIM))[tid];
    float s0 = cur.x + cur.y + cur.z + cur.w;
    float q0 = cur.x*cur.x + cur.y*cur.y + cur.z*cur.z + cur.w*cur.w;
    float s1 = prv.x + prv.y + prv.z + prv.w;
    float q1 = prv.x*prv.x + prv.y*prv.y + prv.z*prv.z + prv.w*prv.w;
    blk_reduce4(s0, q0, s1, q1);
    const float inv = 1.f / (float)DDIM;
    const float m0 = s0 * inv, m1 = s1 * inv;
    const float r0 = rsqrtf(fmaxf(q0 * inv - m0*m0, 0.f) + 1e-5f);
    const float r1 = rsqrtf(fmaxf(q1 * inv - m1*m1, 0.f) + 1e-5f);
    const float4 w4 = ((const float4*)lnw)[tid];
    const float4 b4 = ((const float4*)lnb)[tid];
    const float4 k4 = ((const float4*)mkv)[tid];
    const float4 v4 = ((const float4*)mvv)[tid];
    const float4 r4 = ((const float4*)mrv)[tid];
    const float cA[4] = {cur.x, cur.y, cur.z, cur.w};
    const float pA[4] = {prv.x, prv.y, prv.z, prv.w};
    const float wA[4] = {w4.x, w4.y, w4.z, w4.w};
    const float bA[4] = {b4.x, b4.y, b4.z, b4.w};
    const float kA[4] = {k4.x, k4.y, k4.z, k4.w};
    const float vA[4] = {v4.x, v4.y, v4.z, v4.w};
    const float rA[4] = {r4.x, r4.y, r4.z, r4.w};
    ushort4 pk, pv, pr;
    unsigned short* pkp = &pk.x; unsigned short* pvp = &pv.x; unsigned short* prp = &pr.x;
#pragma unroll
    for (int j = 0; j < 4; ++j) {
        float xa = (cA[j] - m0) * r0 * wA[j] + bA[j];
        float xs = (l > 0) ? ((pA[j] - m1) * r1 * wA[j] + bA[j]) : 0.f;
        pkp[j] = f2bf(xa * kA[j] + xs * (1.f - kA[j]));
        pvp[j] = f2bf(xa * vA[j] + xs * (1.f - vA[j]));
        prp[j] = f2bf(xa * rA[j] + xs * (1.f - rA[j]));
    }
    const size_t oi = (size_t)row * (DDIM/4) + tid;
    ((ushort4*)ok)[oi]  = pk;
    ((ushort4*)ov)[oi]  = pv;
    ((ushort4*)orr)[oi] = pr;
}

// ---------------- LN + time_shift + mix (FFN: 2 outputs) ----------------
__global__ __launch_bounds__(256) void ln_mix2(
    const float* __restrict__ xin, const float* __restrict__ lnw, const float* __restrict__ lnb,
    const float* __restrict__ mkv, const float* __restrict__ mrv,
    __bf16* __restrict__ ok, __bf16* __restrict__ orr)
{
    const int row = blockIdx.x;
    const int l   = row & (LSEQ - 1);
    const int tid = threadIdx.x;
    const size_t rbase = (size_t)row * DDIM;
    const float4 cur = ((const float4*)(xin + rbase))[tid];
    float4 prv = make_float4(0.f, 0.f, 0.f, 0.f);
    if (l > 0) prv = ((const float4*)(xin + rbase - DDIM))[tid];
    float s0 = cur.x + cur.y + cur.z + cur.w;
    float q0 = cur.x*cur.x + cur.y*cur.y + cur.z*cur.z + cur.w*cur.w;
    float s1 = prv.x + prv.y + prv.z + prv.w;
    float q1 = prv.x*prv.x + prv.y*prv.y + prv.z*prv.z + prv.w*prv.w;
    blk_reduce4(s0, q0, s1, q1);
    const float inv = 1.f / (float)DDIM;
    const float m0 = s0 * inv, m1 = s1 * inv;
    const float r0 = rsqrtf(fmaxf(q0 * inv - m0*m0, 0.f) + 1e-5f);
    const float r1 = rsqrtf(fmaxf(q1 * inv - m1*m1, 0.f) + 1e-5f);
    const float4 w4 = ((const float4*)lnw)[tid];
    const float4 b4 = ((const float4*)lnb)[tid];
    const float4 k4 = ((const float4*)mkv)[tid];
    const float4 r4 = ((const float4*)mrv)[tid];
    const float cA[4] = {cur.x, cur.y, cur.z, cur.w};
    const float pA[4] = {prv.x, prv.y, prv.z, prv.w};
    const float wA[4] = {w4.x, w4.y, w4.z, w4.w};
    const float bA[4] = {b4.x, b4.y, b4.z, b4.w};
    const float kA[4] = {k4.x, k4.y, k4.z, k4.w};
    const float rA[4] = {r4.x, r4.y, r4.z, r4.w};
    ushort4 pk, pr;
    unsigned short* pkp = &pk.x; unsigned short* prp = &pr.x;
#pragma unroll
    for (int j = 0; j < 4; ++j) {
        float xa = (cA[j] - m0) * r0 * wA[j] + bA[j];
        float xs = (l > 0) ? ((pA[j] - m1) * r1 * wA[j] + bA[j]) : 0.f;
        pkp[j] = f2bf(xa * kA[j] + xs * (1.f - kA[j]));
        prp[j] = f2bf(xa * rA[j] + xs * (1.f - rA[j]));
    }
    const size_t oi = (size_t)row * (DDIM/4) + tid;
    ((ushort4*)ok)[oi]  = pk;
    ((ushort4*)orr)[oi] = pr;
}

// ---------------- WKV recurrence (fp32 state, bf16 streams, serial over L) ----------------
__global__ __launch_bounds__(64) void wkv_kernel(
    const __bf16* __restrict__ kin, const __bf16* __restrict__ vin,
    const __bf16* __restrict__ srin,
    const float* __restrict__ td, const float* __restrict__ tf,
    __bf16* __restrict__ outp)
{
    const int idx = blockIdx.x * 64 + threadIdx.x;   // 0..B*D-1
    const int d = idx & (DDIM - 1);
    const int b = idx >> 10;
    const float w = -__expf(td[d]);
    const float u = tf[d];
    const size_t base = (size_t)b * LSEQ * DDIM + d;
    float a = 0.f, bb = 0.f, p = -1e38f;
    float kt = (float)kin[base], vt = (float)vin[base];
    float sr = (float)srin[base];
    for (int t = 0; t < LSEQ; ++t) {
        // prefetch next step
        float kn = 0.f, vn = 0.f, sn = 0.f;
        if (t < LSEQ - 1) {
            const size_t nx = base + (size_t)(t + 1) * DDIM;
            kn = (float)kin[nx]; vn = (float)vin[nx]; sn = (float)srin[nx];
        }
        const float ww = u + kt;
        const float q  = fmaxf(p, ww);
        const float e1 = __expf(p - q);
        const float e2 = __expf(ww - q);
        const float o  = (e1 * a + e2 * vt) / (e1 * bb + e2);
        outp[base + (size_t)t * DDIM] = (__bf16)(sr * o);
        const float ww2 = p + w;
        const float q2  = fmaxf(ww2, kt);
        const float e1b = __expf(ww2 - q2);
        const float e2b = __expf(kt - q2);
        a  = e1b * a  + e2b * vt;
        bb = e1b * bb + e2b;
        p  = q2;
        kt = kn; vt = vn; sr = sn;
    }
}

// ---------------- bf16 GEMM: C[M,N] = A[M,K] @ B[N,K]^T, fused epilogues ----------------
// EPI: 1 = sigmoid -> bf16; 2 = relu^2 -> bf16; 3 = auxF + acc -> f32;
//      4 = auxF + (f32)auxH * acc -> f32 (auxF aliases outF); 5 = plain bf16
template<int EPI>
__global__ __launch_bounds__(256)
void gemm_bt(const __bf16* __restrict__ A, const __bf16* __restrict__ Bw,
             float* outF, __bf16* outH,
             const float* auxF, const __bf16* __restrict__ auxH,
             int N, int K)
{
    __shared__ __bf16 As[128 * 32];
    __shared__ __bf16 Bs[128 * 32];
    const int tid  = threadIdx.x;
    const int lane = tid & 63;
    const int wid  = tid >> 6;
    const int wr = wid >> 1, wc = wid & 1;
    const size_t row0 = (size_t)blockIdx.x * 128;
    const size_t col0 = (size_t)blockIdx.y * 128;

    // staging: chunk c covers 16 rows; lane -> (row=l>>2, col8=(l&3)*8); LDS linear
    const int c0 = wid * 2, c1 = c0 + 1;
    const int srow = lane >> 2;
    const int scol = (lane & 3) << 3;
    const __bf16* aG0 = A  + (row0 + c0 * 16 + srow) * (size_t)K + scol;
    const __bf16* aG1 = A  + (row0 + c1 * 16 + srow) * (size_t)K + scol;
    const __bf16* bG0 = Bw + (col0 + c0 * 16 + srow) * (size_t)K + scol;
    const __bf16* bG1 = Bw + (col0 + c1 * 16 + srow) * (size_t)K + scol;
    __bf16* aL0 = &As[c0 * 512];
    __bf16* aL1 = &As[c1 * 512];
    __bf16* bL0 = &Bs[c0 * 512];
    __bf16* bL1 = &Bs[c1 * 512];

    f32x4 acc[4][4] = {};

    // fragment: row = lane&15 within 16-row subtile, k = 8*(lane>>4)+0..7 (contiguous)
    const int aoff = (wr * 64 + (lane & 15)) * 32 + ((lane >> 4) << 3);
    const int boff = (wc * 64 + (lane & 15)) * 32 + ((lane >> 4) << 3);

    for (int k0 = 0; k0 < K; k0 += 32) {
        __syncthreads();                  // previous reads done before overwrite
        gload16(aG0 + k0, aL0);
        gload16(aG1 + k0, aL1);
        gload16(bG0 + k0, bL0);
        gload16(bG1 + k0, bL1);
        __syncthreads();                  // drains vmcnt(0), publishes tile
        u32x4 af[4], bf[4];
#pragma unroll
        for (int m = 0; m < 4; ++m) af[m] = *(const u32x4*)&As[aoff + m * 512];
#pragma unroll
        for (int n = 0; n < 4; ++n) bf[n] = *(const u32x4*)&Bs[boff + n * 512];
#pragma unroll
        for (int m = 0; m < 4; ++m)
#pragma unroll
            for (int n = 0; n < 4; ++n)
                mfma_bf16(acc[m][n], af[m], bf[n]);
    }
    // MFMA->VALU hazard insurance (inline-asm MFMA; compiler may not pad)
    asm volatile("s_nop 7\n\ts_nop 7\n\ts_nop 3");

    // C/D layout: col = lane&15, row = 4*(lane>>4) + reg   [m89/m91-verified]
    const size_t obr = row0 + wr * 64 + ((lane >> 4) << 2);
    const size_t obc = col0 + wc * 64 + (lane & 15);
#pragma unroll
    for (int m = 0; m < 4; ++m) {
#pragma unroll
        for (int n = 0; n < 4; ++n) {
#pragma unroll
            for (int j = 0; j < 4; ++j) {
                const size_t idx = (obr + m * 16 + j) * (size_t)N + obc + n * 16;
                const float v = acc[m][n][j];
                if constexpr (EPI == 1) {
                    outH[idx] = (__bf16)(1.f / (1.f + __expf(-v)));
                } else if constexpr (EPI == 2) {
                    const float t = fmaxf(v, 0.f);
                    outH[idx] = (__bf16)(t * t);
                } else if constexpr (EPI == 3) {
                    outF[idx] = auxF[idx] + v;
                } else if constexpr (EPI == 4) {
                    outF[idx] = auxF[idx] + (float)auxH[idx] * v;
                } else {
                    outH[idx] = (__bf16)v;
                }
            }
        }
    }
}

extern "C" void kernel_launch(void* const* d_in, const int* in_sizes, int n_in,
                              void* d_out, int out_size, void* d_ws, size_t ws_size,
                              hipStream_t stream)
{
    const float* x    = (const float*)d_in[0];
    const float* lnaw = (const float*)d_in[1];
    const float* lnab = (const float*)d_in[2];
    const float* lnfw = (const float*)d_in[3];
    const float* lnfb = (const float*)d_in[4];
    const float* tdec = (const float*)d_in[5];
    const float* tfir = (const float*)d_in[6];
    const float* amk  = (const float*)d_in[7];
    const float* amv  = (const float*)d_in[8];
    const float* amr  = (const float*)d_in[9];
    const float* aWk  = (const float*)d_in[10];
    const float* aWv  = (const float*)d_in[11];
    const float* aWr  = (const float*)d_in[12];
    const float* aWo  = (const float*)d_in[13];
    const float* fmk  = (const float*)d_in[14];
    const float* fmr  = (const float*)d_in[15];
    const float* fWk  = (const float*)d_in[16];
    const float* fWv  = (const float*)d_in[17];
    const float* fWr  = (const float*)d_in[18];
    float* out = (float*)d_out;

    char* ws = (char*)d_ws;
    const size_t MiB = 1ull << 20;
    // weights (bf16): 13M elements = 26 MiB @ [0, 26)
    __bf16* Wk_h  = (__bf16*)ws;
    __bf16* Wv_h  = Wk_h + (1ull << 20);
    __bf16* Wr_h  = Wk_h + (2ull << 20);
    __bf16* Wo_h  = Wk_h + (3ull << 20);
    __bf16* fWk_h = Wk_h + (4ull << 20);
    __bf16* fWv_h = Wk_h + (8ull << 20);
    __bf16* fWr_h = Wk_h + (12ull << 20);
    // activations — peak ws extent = 218 MiB
    __bf16* xk = (__bf16*)(ws + 26 * MiB);   // [26,58)
    __bf16* xv = (__bf16*)(ws + 58 * MiB);   // [58,90)
    __bf16* xr = (__bf16*)(ws + 90 * MiB);   // [90,122)
    __bf16* kb = (__bf16*)(ws + 122 * MiB);  // [122,154)
    __bf16* vb = (__bf16*)(ws + 154 * MiB);  // [154,186)
    __bf16* sr = (__bf16*)(ws + 186 * MiB);  // [186,218)
    __bf16* atta = xk;                       // xk dead after k-GEMM
    __bf16* kx   = xv;                       // xv dead after v-GEMM
    __bf16* rx   = xr;                       // xr dead after r-GEMM
    __bf16* sb   = xk;                       // atta dead after Wo-GEMM
    __bf16* hb   = (__bf16*)(ws + 90 * MiB); // [90,218) over rx+kb+vb+sr (all dead)

    // 1. weights -> bf16
    cvt_bf16<<<1024, 256, 0, stream>>>(aWk, Wk_h,  1 << 18);
    cvt_bf16<<<1024, 256, 0, stream>>>(aWv, Wv_h,  1 << 18);
    cvt_bf16<<<1024, 256, 0, stream>>>(aWr, Wr_h,  1 << 18);
    cvt_bf16<<<1024, 256, 0, stream>>>(aWo, Wo_h,  1 << 18);
    cvt_bf16<<<4096, 256, 0, stream>>>(fWk, fWk_h, 1 << 20);
    cvt_bf16<<<4096, 256, 0, stream>>>(fWv, fWv_h, 1 << 20);
    cvt_bf16<<<1024, 256, 0, stream>>>(fWr, fWr_h, 1 << 18);

    // 2. attention LN + shift + mix
    ln_mix3<<<MROWS, 256, 0, stream>>>(x, lnaw, lnab, amk, amv, amr, xk, xv, xr);

    // 3. k, v (bf16), sigmoid(r)
    dim3 blk(256);
    dim3 gD(MROWS / 128, DDIM / 128);
    gemm_bt<5><<<gD, blk, 0, stream>>>(xk, Wk_h, nullptr, kb, nullptr, nullptr, DDIM, DDIM);
    gemm_bt<5><<<gD, blk, 0, stream>>>(xv, Wv_h, nullptr, vb, nullptr, nullptr, DDIM, DDIM);
    gemm_bt<1><<<gD, blk, 0, stream>>>(xr, Wr_h, nullptr, sr, nullptr, nullptr, DDIM, DDIM);

    // 4. WKV scan -> sigmoid(r) * wkv (bf16), overwrites xk region
    wkv_kernel<<<(BSZ * DDIM) / 64, 64, 0, stream>>>(kb, vb, sr, tdec, tfir, atta);

    // 5. att output projection + residual -> d_out (= x_new)
    gemm_bt<3><<<gD, blk, 0, stream>>>(atta, Wo_h, out, nullptr, x, nullptr, DDIM, DDIM);

    // 6. FFN LN + shift + mix (reads d_out)
    ln_mix2<<<MROWS, 256, 0, stream>>>(out, lnfw, lnfb, fmk, fmr, kx, rx);

    // 7a. s = sigmoid(rx @ fWr^T)  (BEFORE h so rx region can be reused by h)
    gemm_bt<1><<<gD, blk, 0, stream>>>(rx, fWr_h, nullptr, sb, nullptr, nullptr, DDIM, DDIM);

    // 7b. h = relu(kx @ fWk^T)^2  -> [90,218)
    dim3 gF(MROWS / 128, FDIM / 128);
    gemm_bt<2><<<gF, blk, 0, stream>>>(kx, fWk_h, nullptr, hb, nullptr, nullptr, FDIM, DDIM);

    // 8. d_out = x_new + s * (h @ fWv^T)   (in-place residual, per-thread RMW)
    gemm_bt<4><<<gD, blk, 0, stream>>>(hb, fWv_h, out, nullptr, out, sb, DDIM, FDIM);
}

// Round 3
// 796.333 us; speedup vs baseline: 1.5362x; 1.5362x over previous
//
#include <hip/hip_runtime.h>
#include <stdint.h>

// Problem dims (fixed by harness)
#define DDIM 1024
#define LSEQ 2048
#define BSZ  8
#define FDIM 4096
#define MROWS (BSZ*LSEQ)   // 16384
#define NCHUNK 32
#define CLEN  (LSEQ/NCHUNK)   // 64

typedef float        f32x4  __attribute__((ext_vector_type(4)));
typedef unsigned int u32x4  __attribute__((ext_vector_type(4)));

using gas_void = const __attribute__((address_space(1))) void;
using las_void = __attribute__((address_space(3))) void;

__device__ __forceinline__ void gload16(const void* g, void* l) {
    // async global->LDS, 16B per lane; LDS dest = wave-uniform base + lane*16
    __builtin_amdgcn_global_load_lds((gas_void*)g, (las_void*)l, 16, 0, 0);
}

__device__ __forceinline__ void mfma_bf16(f32x4& d, u32x4 a, u32x4 b) {
    asm("v_mfma_f32_16x16x32_bf16 %0, %1, %2, %0" : "+v"(d) : "v"(a), "v"(b));
}

__device__ __forceinline__ unsigned short f2bf(float f) {
    __bf16 h = (__bf16)f;
    return __builtin_bit_cast(unsigned short, h);
}

// ---------------- weight fp32 -> bf16 ----------------
__global__ __launch_bounds__(256) void cvt_bf16(const float* __restrict__ src,
                                                __bf16* __restrict__ dst, int n4)
{
    int i = blockIdx.x * 256 + threadIdx.x;
    if (i >= n4) return;
    float4 f = ((const float4*)src)[i];
    ushort4 o;
    o.x = f2bf(f.x); o.y = f2bf(f.y); o.z = f2bf(f.z); o.w = f2bf(f.w);
    ((ushort4*)dst)[i] = o;
}

// ---------------- block reduce (4 scalars over 256 threads) ----------------
__device__ __forceinline__ void blk_reduce4(float& a, float& b, float& c, float& d) {
#pragma unroll
    for (int off = 32; off >= 1; off >>= 1) {
        a += __shfl_xor(a, off, 64);
        b += __shfl_xor(b, off, 64);
        c += __shfl_xor(c, off, 64);
        d += __shfl_xor(d, off, 64);
    }
    __shared__ float sm[4][4];
    const int tid = threadIdx.x;
    if ((tid & 63) == 0) {
        sm[tid >> 6][0] = a; sm[tid >> 6][1] = b;
        sm[tid >> 6][2] = c; sm[tid >> 6][3] = d;
    }
    __syncthreads();
    a = sm[0][0] + sm[1][0] + sm[2][0] + sm[3][0];
    b = sm[0][1] + sm[1][1] + sm[2][1] + sm[3][1];
    c = sm[0][2] + sm[1][2] + sm[2][2] + sm[3][2];
    d = sm[0][3] + sm[1][3] + sm[2][3] + sm[3][3];
}

// ---------------- LN + time_shift + mix (attention: 3 outputs) ----------------
__global__ __launch_bounds__(256) void ln_mix3(
    const float* __restrict__ xin, const float* __restrict__ lnw, const float* __restrict__ lnb,
    const float* __restrict__ mkv, const float* __restrict__ mvv, const float* __restrict__ mrv,
    __bf16* __restrict__ ok, __bf16* __restrict__ ov, __bf16* __restrict__ orr)
{
    const int row = blockIdx.x;          // b*L + l
    const int l   = row & (LSEQ - 1);
    const int tid = threadIdx.x;
    const size_t rbase = (size_t)row * DDIM;
    const float4 cur = ((const float4*)(xin + rbase))[tid];
    float4 prv = make_float4(0.f, 0.f, 0.f, 0.f);
    if (l > 0) prv = ((const float4*)(xin + rbase - DDIM))[tid];
    float s0 = cur.x + cur.y + cur.z + cur.w;
    float q0 = cur.x*cur.x + cur.y*cur.y + cur.z*cur.z + cur.w*cur.w;
    float s1 = prv.x + prv.y + prv.z + prv.w;
    float q1 = prv.x*prv.x + prv.y*prv.y + prv.z*prv.z + prv.w*prv.w;
    blk_reduce4(s0, q0, s1, q1);
    const float inv = 1.f / (float)DDIM;
    const float m0 = s0 * inv, m1 = s1 * inv;
    const float r0 = rsqrtf(fmaxf(q0 * inv - m0*m0, 0.f) + 1e-5f);
    const float r1 = rsqrtf(fmaxf(q1 * inv - m1*m1, 0.f) + 1e-5f);
    const float4 w4 = ((const float4*)lnw)[tid];
    const float4 b4 = ((const float4*)lnb)[tid];
    const float4 k4 = ((const float4*)mkv)[tid];
    const float4 v4 = ((const float4*)mvv)[tid];
    const float4 r4 = ((const float4*)mrv)[tid];
    const float cA[4] = {cur.x, cur.y, cur.z, cur.w};
    const float pA[4] = {prv.x, prv.y, prv.z, prv.w};
    const float wA[4] = {w4.x, w4.y, w4.z, w4.w};
    const float bA[4] = {b4.x, b4.y, b4.z, b4.w};
    const float kA[4] = {k4.x, k4.y, k4.z, k4.w};
    const float vA[4] = {v4.x, v4.y, v4.z, v4.w};
    const float rA[4] = {r4.x, r4.y, r4.z, r4.w};
    ushort4 pk, pv, pr;
    unsigned short* pkp = &pk.x; unsigned short* pvp = &pv.x; unsigned short* prp = &pr.x;
#pragma unroll
    for (int j = 0; j < 4; ++j) {
        float xa = (cA[j] - m0) * r0 * wA[j] + bA[j];
        float xs = (l > 0) ? ((pA[j] - m1) * r1 * wA[j] + bA[j]) : 0.f;
        pkp[j] = f2bf(xa * kA[j] + xs * (1.f - kA[j]));
        pvp[j] = f2bf(xa * vA[j] + xs * (1.f - vA[j]));
        prp[j] = f2bf(xa * rA[j] + xs * (1.f - rA[j]));
    }
    const size_t oi = (size_t)row * (DDIM/4) + tid;
    ((ushort4*)ok)[oi]  = pk;
    ((ushort4*)ov)[oi]  = pv;
    ((ushort4*)orr)[oi] = pr;
}

// ---------------- LN + time_shift + mix (FFN: 2 outputs) ----------------
__global__ __launch_bounds__(256) void ln_mix2(
    const float* __restrict__ xin, const float* __restrict__ lnw, const float* __restrict__ lnb,
    const float* __restrict__ mkv, const float* __restrict__ mrv,
    __bf16* __restrict__ ok, __bf16* __restrict__ orr)
{
    const int row = blockIdx.x;
    const int l   = row & (LSEQ - 1);
    const int tid = threadIdx.x;
    const size_t rbase = (size_t)row * DDIM;
    const float4 cur = ((const float4*)(xin + rbase))[tid];
    float4 prv = make_float4(0.f, 0.f, 0.f, 0.f);
    if (l > 0) prv = ((const float4*)(xin + rbase - DDIM))[tid];
    float s0 = cur.x + cur.y + cur.z + cur.w;
    float q0 = cur.x*cur.x + cur.y*cur.y + cur.z*cur.z + cur.w*cur.w;
    float s1 = prv.x + prv.y + prv.z + prv.w;
    float q1 = prv.x*prv.x + prv.y*prv.y + prv.z*prv.z + prv.w*prv.w;
    blk_reduce4(s0, q0, s1, q1);
    const float inv = 1.f / (float)DDIM;
    const float m0 = s0 * inv, m1 = s1 * inv;
    const float r0 = rsqrtf(fmaxf(q0 * inv - m0*m0, 0.f) + 1e-5f);
    const float r1 = rsqrtf(fmaxf(q1 * inv - m1*m1, 0.f) + 1e-5f);
    const float4 w4 = ((const float4*)lnw)[tid];
    const float4 b4 = ((const float4*)lnb)[tid];
    const float4 k4 = ((const float4*)mkv)[tid];
    const float4 r4 = ((const float4*)mrv)[tid];
    const float cA[4] = {cur.x, cur.y, cur.z, cur.w};
    const float pA[4] = {prv.x, prv.y, prv.z, prv.w};
    const float wA[4] = {w4.x, w4.y, w4.z, w4.w};
    const float bA[4] = {b4.x, b4.y, b4.z, b4.w};
    const float kA[4] = {k4.x, k4.y, k4.z, k4.w};
    const float rA[4] = {r4.x, r4.y, r4.z, r4.w};
    ushort4 pk, pr;
    unsigned short* pkp = &pk.x; unsigned short* prp = &pr.x;
#pragma unroll
    for (int j = 0; j < 4; ++j) {
        float xa = (cA[j] - m0) * r0 * wA[j] + bA[j];
        float xs = (l > 0) ? ((pA[j] - m1) * r1 * wA[j] + bA[j]) : 0.f;
        pkp[j] = f2bf(xa * kA[j] + xs * (1.f - kA[j]));
        prp[j] = f2bf(xa * rA[j] + xs * (1.f - rA[j]));
    }
    const size_t oi = (size_t)row * (DDIM/4) + tid;
    ((ushort4*)ok)[oi]  = pk;
    ((ushort4*)orr)[oi] = pr;
}

// ---------------- WKV chunk-parallel scan ----------------
// idx -> (c, b, d): d = idx&1023, b = (idx>>10)&7, c = idx>>13.
// State arrays indexed by idx directly (c-major layout).

// Phase 1: local scan of chunk c from zero state -> (a, b, p)
__global__ __launch_bounds__(256) void wkv_phase1(
    const __bf16* __restrict__ kin, const __bf16* __restrict__ vin,
    const float* __restrict__ td,
    float* __restrict__ sa, float* __restrict__ sb, float* __restrict__ sp)
{
    const int idx = blockIdx.x * 256 + threadIdx.x;
    const int d  = idx & (DDIM - 1);
    const int bc = idx >> 10;
    const int b  = bc & (BSZ - 1);
    const int c  = bc >> 3;
    const float w = -__expf(td[d]);
    const size_t base = ((size_t)b * LSEQ + (size_t)c * CLEN) * DDIM + d;
    float a = 0.f, bbv = 0.f, p = -1e38f;
    for (int t = 0; t < CLEN; ++t) {
        const size_t off = base + (size_t)t * DDIM;
        const float kt = (float)kin[off];
        const float vt = (float)vin[off];
        const float ww2 = p + w;
        const float q2  = fmaxf(ww2, kt);
        const float e1  = __expf(ww2 - q2);
        const float e2  = __expf(kt - q2);
        a   = e1 * a   + e2 * vt;
        bbv = e1 * bbv + e2;
        p   = q2;
    }
    sa[idx] = a; sb[idx] = bbv; sp[idx] = p;
}

// Phase 2: compose predecessor chunk states, then scan chunk emitting sr*wkv
__global__ __launch_bounds__(256) void wkv_phase2(
    const __bf16* __restrict__ kin, const __bf16* __restrict__ vin,
    const __bf16* __restrict__ srin,
    const float* __restrict__ td, const float* __restrict__ tf,
    const float* __restrict__ sa, const float* __restrict__ sb,
    const float* __restrict__ sp,
    __bf16* __restrict__ outp)
{
    const int idx = blockIdx.x * 256 + threadIdx.x;
    const int d  = idx & (DDIM - 1);
    const int bc = idx >> 10;
    const int b  = bc & (BSZ - 1);
    const int c  = bc >> 3;
    const float w = -__expf(td[d]);
    const float u = tf[d];
    const float nw = (float)CLEN * w;

    // incoming state = compose chunks 0..c-1 (c is block-uniform -> no divergence)
    float a = 0.f, bbv = 0.f, p = -1e38f;
    for (int j = 0; j < c; ++j) {
        const int sidx = ((j * BSZ + b) << 10) + d;
        const float aj = sa[sidx], bj = sb[sidx], pj = sp[sidx];
        const float ps = p + nw;
        const float pn = fmaxf(ps, pj);
        const float e1 = __expf(ps - pn);
        const float e2 = __expf(pj - pn);
        a   = e1 * a   + e2 * aj;
        bbv = e1 * bbv + e2 * bj;
        p   = pn;
    }

    const size_t base = ((size_t)b * LSEQ + (size_t)c * CLEN) * DDIM + d;
    for (int t = 0; t < CLEN; ++t) {
        const size_t off = base + (size_t)t * DDIM;
        const float kt = (float)kin[off];
        const float vt = (float)vin[off];
        const float sr = (float)srin[off];
        const float ww = u + kt;
        const float q  = fmaxf(p, ww);
        const float e1 = __expf(p - q);
        const float e2 = __expf(ww - q);
        const float o  = (e1 * a + e2 * vt) / (e1 * bbv + e2);
        outp[off] = (__bf16)(sr * o);
        const float ww2 = p + w;
        const float q2  = fmaxf(ww2, kt);
        const float e1b = __expf(ww2 - q2);
        const float e2b = __expf(kt - q2);
        a   = e1b * a   + e2b * vt;
        bbv = e1b * bbv + e2b;
        p   = q2;
    }
}

// ---------------- bf16 GEMM: C[M,N] = A[M,K] @ B[N,K]^T, fused epilogues ----------------
// EPI: 1 = sigmoid -> bf16; 2 = relu^2 -> bf16; 3 = auxF + acc -> f32;
//      4 = auxF + (f32)auxH * acc -> f32 (auxF aliases outF); 5 = plain bf16
template<int EPI>
__global__ __launch_bounds__(256)
void gemm_bt(const __bf16* __restrict__ A, const __bf16* __restrict__ Bw,
             float* outF, __bf16* outH,
             const float* auxF, const __bf16* __restrict__ auxH,
             int N, int K)
{
    __shared__ __bf16 As[128 * 32];
    __shared__ __bf16 Bs[128 * 32];
    const int tid  = threadIdx.x;
    const int lane = tid & 63;
    const int wid  = tid >> 6;
    const int wr = wid >> 1, wc = wid & 1;
    const size_t row0 = (size_t)blockIdx.x * 128;
    const size_t col0 = (size_t)blockIdx.y * 128;

    const int c0 = wid * 2, c1 = c0 + 1;
    const int srow = lane >> 2;
    const int scol = (lane & 3) << 3;
    const __bf16* aG0 = A  + (row0 + c0 * 16 + srow) * (size_t)K + scol;
    const __bf16* aG1 = A  + (row0 + c1 * 16 + srow) * (size_t)K + scol;
    const __bf16* bG0 = Bw + (col0 + c0 * 16 + srow) * (size_t)K + scol;
    const __bf16* bG1 = Bw + (col0 + c1 * 16 + srow) * (size_t)K + scol;
    __bf16* aL0 = &As[c0 * 512];
    __bf16* aL1 = &As[c1 * 512];
    __bf16* bL0 = &Bs[c0 * 512];
    __bf16* bL1 = &Bs[c1 * 512];

    f32x4 acc[4][4] = {};

    const int aoff = (wr * 64 + (lane & 15)) * 32 + ((lane >> 4) << 3);
    const int boff = (wc * 64 + (lane & 15)) * 32 + ((lane >> 4) << 3);

    for (int k0 = 0; k0 < K; k0 += 32) {
        __syncthreads();
        gload16(aG0 + k0, aL0);
        gload16(aG1 + k0, aL1);
        gload16(bG0 + k0, bL0);
        gload16(bG1 + k0, bL1);
        __syncthreads();
        u32x4 af[4], bf[4];
#pragma unroll
        for (int m = 0; m < 4; ++m) af[m] = *(const u32x4*)&As[aoff + m * 512];
#pragma unroll
        for (int n = 0; n < 4; ++n) bf[n] = *(const u32x4*)&Bs[boff + n * 512];
#pragma unroll
        for (int m = 0; m < 4; ++m)
#pragma unroll
            for (int n = 0; n < 4; ++n)
                mfma_bf16(acc[m][n], af[m], bf[n]);
    }
    asm volatile("s_nop 7\n\ts_nop 7\n\ts_nop 3");

    const size_t obr = row0 + wr * 64 + ((lane >> 4) << 2);
    const size_t obc = col0 + wc * 64 + (lane & 15);
#pragma unroll
    for (int m = 0; m < 4; ++m) {
#pragma unroll
        for (int n = 0; n < 4; ++n) {
#pragma unroll
            for (int j = 0; j < 4; ++j) {
                const size_t idx = (obr + m * 16 + j) * (size_t)N + obc + n * 16;
                const float v = acc[m][n][j];
                if constexpr (EPI == 1) {
                    outH[idx] = (__bf16)(1.f / (1.f + __expf(-v)));
                } else if constexpr (EPI == 2) {
                    const float t = fmaxf(v, 0.f);
                    outH[idx] = (__bf16)(t * t);
                } else if constexpr (EPI == 3) {
                    outF[idx] = auxF[idx] + v;
                } else if constexpr (EPI == 4) {
                    outF[idx] = auxF[idx] + (float)auxH[idx] * v;
                } else {
                    outH[idx] = (__bf16)v;
                }
            }
        }
    }
}

extern "C" void kernel_launch(void* const* d_in, const int* in_sizes, int n_in,
                              void* d_out, int out_size, void* d_ws, size_t ws_size,
                              hipStream_t stream)
{
    const float* x    = (const float*)d_in[0];
    const float* lnaw = (const float*)d_in[1];
    const float* lnab = (const float*)d_in[2];
    const float* lnfw = (const float*)d_in[3];
    const float* lnfb = (const float*)d_in[4];
    const float* tdec = (const float*)d_in[5];
    const float* tfir = (const float*)d_in[6];
    const float* amk  = (const float*)d_in[7];
    const float* amv  = (const float*)d_in[8];
    const float* amr  = (const float*)d_in[9];
    const float* aWk  = (const float*)d_in[10];
    const float* aWv  = (const float*)d_in[11];
    const float* aWr  = (const float*)d_in[12];
    const float* aWo  = (const float*)d_in[13];
    const float* fmk  = (const float*)d_in[14];
    const float* fmr  = (const float*)d_in[15];
    const float* fWk  = (const float*)d_in[16];
    const float* fWv  = (const float*)d_in[17];
    const float* fWr  = (const float*)d_in[18];
    float* out = (float*)d_out;

    char* ws = (char*)d_ws;
    const size_t MiB = 1ull << 20;
    // weights (bf16): 13M elements = 26 MiB @ [0, 26)
    __bf16* Wk_h  = (__bf16*)ws;
    __bf16* Wv_h  = Wk_h + (1ull << 20);
    __bf16* Wr_h  = Wk_h + (2ull << 20);
    __bf16* Wo_h  = Wk_h + (3ull << 20);
    __bf16* fWk_h = Wk_h + (4ull << 20);
    __bf16* fWv_h = Wk_h + (8ull << 20);
    __bf16* fWr_h = Wk_h + (12ull << 20);
    // activations — peak ws extent = 221 MiB
    __bf16* xk = (__bf16*)(ws + 26 * MiB);   // [26,58)
    __bf16* xv = (__bf16*)(ws + 58 * MiB);   // [58,90)
    __bf16* xr = (__bf16*)(ws + 90 * MiB);   // [90,122)
    __bf16* kb = (__bf16*)(ws + 122 * MiB);  // [122,154)
    __bf16* vb = (__bf16*)(ws + 154 * MiB);  // [154,186)
    __bf16* sr = (__bf16*)(ws + 186 * MiB);  // [186,218)
    float* st_a = (float*)(ws + 218 * MiB);  // [218,219) — 1 MiB each
    float* st_b = (float*)(ws + 219 * MiB);
    float* st_p = (float*)(ws + 220 * MiB);  // end 221 MiB
    __bf16* atta = xk;                       // xk dead after k-GEMM
    __bf16* kx   = xv;                       // xv dead after v-GEMM
    __bf16* rx   = xr;                       // xr dead after r-GEMM
    __bf16* sb   = xk;                       // atta dead after Wo-GEMM
    __bf16* hb   = (__bf16*)(ws + 90 * MiB); // [90,218) over rx+kb+vb+sr (all dead)

    // 1. weights -> bf16
    cvt_bf16<<<1024, 256, 0, stream>>>(aWk, Wk_h,  1 << 18);
    cvt_bf16<<<1024, 256, 0, stream>>>(aWv, Wv_h,  1 << 18);
    cvt_bf16<<<1024, 256, 0, stream>>>(aWr, Wr_h,  1 << 18);
    cvt_bf16<<<1024, 256, 0, stream>>>(aWo, Wo_h,  1 << 18);
    cvt_bf16<<<4096, 256, 0, stream>>>(fWk, fWk_h, 1 << 20);
    cvt_bf16<<<4096, 256, 0, stream>>>(fWv, fWv_h, 1 << 20);
    cvt_bf16<<<1024, 256, 0, stream>>>(fWr, fWr_h, 1 << 18);

    // 2. attention LN + shift + mix
    ln_mix3<<<MROWS, 256, 0, stream>>>(x, lnaw, lnab, amk, amv, amr, xk, xv, xr);

    // 3. k, v (bf16), sigmoid(r)
    dim3 blk(256);
    dim3 gD(MROWS / 128, DDIM / 128);
    gemm_bt<5><<<gD, blk, 0, stream>>>(xk, Wk_h, nullptr, kb, nullptr, nullptr, DDIM, DDIM);
    gemm_bt<5><<<gD, blk, 0, stream>>>(xv, Wv_h, nullptr, vb, nullptr, nullptr, DDIM, DDIM);
    gemm_bt<1><<<gD, blk, 0, stream>>>(xr, Wr_h, nullptr, sr, nullptr, nullptr, DDIM, DDIM);

    // 4. WKV chunk-parallel scan -> sigmoid(r) * wkv (bf16), into xk region
    const int nthreads = BSZ * DDIM * NCHUNK;   // 262144
    wkv_phase1<<<nthreads / 256, 256, 0, stream>>>(kb, vb, tdec, st_a, st_b, st_p);
    wkv_phase2<<<nthreads / 256, 256, 0, stream>>>(kb, vb, sr, tdec, tfir,
                                                   st_a, st_b, st_p, atta);

    // 5. att output projection + residual -> d_out (= x_new)
    gemm_bt<3><<<gD, blk, 0, stream>>>(atta, Wo_h, out, nullptr, x, nullptr, DDIM, DDIM);

    // 6. FFN LN + shift + mix (reads d_out)
    ln_mix2<<<MROWS, 256, 0, stream>>>(out, lnfw, lnfb, fmk, fmr, kx, rx);

    // 7a. s = sigmoid(rx @ fWr^T)  (BEFORE h so rx region can be reused by h)
    gemm_bt<1><<<gD, blk, 0, stream>>>(rx, fWr_h, nullptr, sb, nullptr, nullptr, DDIM, DDIM);

    // 7b. h = relu(kx @ fWk^T)^2  -> [90,218)
    dim3 gF(MROWS / 128, FDIM / 128);
    gemm_bt<2><<<gF, blk, 0, stream>>>(kx, fWk_h, nullptr, hb, nullptr, nullptr, FDIM, DDIM);

    // 8. d_out = x_new + s * (h @ fWv^T)   (in-place residual, per-thread RMW)
    gemm_bt<4><<<gD, blk, 0, stream>>>(hb, fWv_h, out, nullptr, out, sb, DDIM, FDIM);
}

// Round 4
// 737.355 us; speedup vs baseline: 1.6591x; 1.0800x over previous
//
#include <hip/hip_runtime.h>
#include <stdint.h>

// Problem dims (fixed by harness)
#define DDIM 1024
#define LSEQ 2048
#define BSZ  8
#define FDIM 4096
#define MROWS (BSZ*LSEQ)   // 16384
#define NCHUNK 32
#define CLEN  (LSEQ/NCHUNK)   // 64

typedef float        f32x4  __attribute__((ext_vector_type(4)));
typedef unsigned int u32x4  __attribute__((ext_vector_type(4)));

using gas_void = const __attribute__((address_space(1))) void;
using las_void = __attribute__((address_space(3))) void;

__device__ __forceinline__ void gload16(const void* g, void* l) {
    // async global->LDS, 16B per lane; LDS dest = wave-uniform base + lane*16
    __builtin_amdgcn_global_load_lds((gas_void*)g, (las_void*)l, 16, 0, 0);
}

__device__ __forceinline__ void mfma_bf16(f32x4& d, u32x4 a, u32x4 b) {
    asm("v_mfma_f32_16x16x32_bf16 %0, %1, %2, %0" : "+v"(d) : "v"(a), "v"(b));
}

__device__ __forceinline__ unsigned short f2bf(float f) {
    __bf16 h = (__bf16)f;
    return __builtin_bit_cast(unsigned short, h);
}

// ---------------- weight fp32 -> bf16 ----------------
__global__ __launch_bounds__(256) void cvt_bf16(const float* __restrict__ src,
                                                __bf16* __restrict__ dst, int n4)
{
    int i = blockIdx.x * 256 + threadIdx.x;
    if (i >= n4) return;
    float4 f = ((const float4*)src)[i];
    ushort4 o;
    o.x = f2bf(f.x); o.y = f2bf(f.y); o.z = f2bf(f.z); o.w = f2bf(f.w);
    ((ushort4*)dst)[i] = o;
}

// ---------------- block reduce (4 scalars over 256 threads) ----------------
__device__ __forceinline__ void blk_reduce4(float& a, float& b, float& c, float& d) {
#pragma unroll
    for (int off = 32; off >= 1; off >>= 1) {
        a += __shfl_xor(a, off, 64);
        b += __shfl_xor(b, off, 64);
        c += __shfl_xor(c, off, 64);
        d += __shfl_xor(d, off, 64);
    }
    __shared__ float sm[4][4];
    const int tid = threadIdx.x;
    if ((tid & 63) == 0) {
        sm[tid >> 6][0] = a; sm[tid >> 6][1] = b;
        sm[tid >> 6][2] = c; sm[tid >> 6][3] = d;
    }
    __syncthreads();
    a = sm[0][0] + sm[1][0] + sm[2][0] + sm[3][0];
    b = sm[0][1] + sm[1][1] + sm[2][1] + sm[3][1];
    c = sm[0][2] + sm[1][2] + sm[2][2] + sm[3][2];
    d = sm[0][3] + sm[1][3] + sm[2][3] + sm[3][3];
}

// ---------------- LN + time_shift + mix (attention: 3 outputs) ----------------
__global__ __launch_bounds__(256) void ln_mix3(
    const float* __restrict__ xin, const float* __restrict__ lnw, const float* __restrict__ lnb,
    const float* __restrict__ mkv, const float* __restrict__ mvv, const float* __restrict__ mrv,
    __bf16* __restrict__ ok, __bf16* __restrict__ ov, __bf16* __restrict__ orr)
{
    const int row = blockIdx.x;          // b*L + l
    const int l   = row & (LSEQ - 1);
    const int tid = threadIdx.x;
    const size_t rbase = (size_t)row * DDIM;
    const float4 cur = ((const float4*)(xin + rbase))[tid];
    float4 prv = make_float4(0.f, 0.f, 0.f, 0.f);
    if (l > 0) prv = ((const float4*)(xin + rbase - DDIM))[tid];
    float s0 = cur.x + cur.y + cur.z + cur.w;
    float q0 = cur.x*cur.x + cur.y*cur.y + cur.z*cur.z + cur.w*cur.w;
    float s1 = prv.x + prv.y + prv.z + prv.w;
    float q1 = prv.x*prv.x + prv.y*prv.y + prv.z*prv.z + prv.w*prv.w;
    blk_reduce4(s0, q0, s1, q1);
    const float inv = 1.f / (float)DDIM;
    const float m0 = s0 * inv, m1 = s1 * inv;
    const float r0 = rsqrtf(fmaxf(q0 * inv - m0*m0, 0.f) + 1e-5f);
    const float r1 = rsqrtf(fmaxf(q1 * inv - m1*m1, 0.f) + 1e-5f);
    const float4 w4 = ((const float4*)lnw)[tid];
    const float4 b4 = ((const float4*)lnb)[tid];
    const float4 k4 = ((const float4*)mkv)[tid];
    const float4 v4 = ((const float4*)mvv)[tid];
    const float4 r4 = ((const float4*)mrv)[tid];
    const float cA[4] = {cur.x, cur.y, cur.z, cur.w};
    const float pA[4] = {prv.x, prv.y, prv.z, prv.w};
    const float wA[4] = {w4.x, w4.y, w4.z, w4.w};
    const float bA[4] = {b4.x, b4.y, b4.z, b4.w};
    const float kA[4] = {k4.x, k4.y, k4.z, k4.w};
    const float vA[4] = {v4.x, v4.y, v4.z, v4.w};
    const float rA[4] = {r4.x, r4.y, r4.z, r4.w};
    ushort4 pk, pv, pr;
    unsigned short* pkp = &pk.x; unsigned short* pvp = &pv.x; unsigned short* prp = &pr.x;
#pragma unroll
    for (int j = 0; j < 4; ++j) {
        float xa = (cA[j] - m0) * r0 * wA[j] + bA[j];
        float xs = (l > 0) ? ((pA[j] - m1) * r1 * wA[j] + bA[j]) : 0.f;
        pkp[j] = f2bf(xa * kA[j] + xs * (1.f - kA[j]));
        pvp[j] = f2bf(xa * vA[j] + xs * (1.f - vA[j]));
        prp[j] = f2bf(xa * rA[j] + xs * (1.f - rA[j]));
    }
    const size_t oi = (size_t)row * (DDIM/4) + tid;
    ((ushort4*)ok)[oi]  = pk;
    ((ushort4*)ov)[oi]  = pv;
    ((ushort4*)orr)[oi] = pr;
}

// ---------------- LN + time_shift + mix (FFN: 2 outputs) ----------------
__global__ __launch_bounds__(256) void ln_mix2(
    const float* __restrict__ xin, const float* __restrict__ lnw, const float* __restrict__ lnb,
    const float* __restrict__ mkv, const float* __restrict__ mrv,
    __bf16* __restrict__ ok, __bf16* __restrict__ orr)
{
    const int row = blockIdx.x;
    const int l   = row & (LSEQ - 1);
    const int tid = threadIdx.x;
    const size_t rbase = (size_t)row * DDIM;
    const float4 cur = ((const float4*)(xin + rbase))[tid];
    float4 prv = make_float4(0.f, 0.f, 0.f, 0.f);
    if (l > 0) prv = ((const float4*)(xin + rbase - DDIM))[tid];
    float s0 = cur.x + cur.y + cur.z + cur.w;
    float q0 = cur.x*cur.x + cur.y*cur.y + cur.z*cur.z + cur.w*cur.w;
    float s1 = prv.x + prv.y + prv.z + prv.w;
    float q1 = prv.x*prv.x + prv.y*prv.y + prv.z*prv.z + prv.w*prv.w;
    blk_reduce4(s0, q0, s1, q1);
    const float inv = 1.f / (float)DDIM;
    const float m0 = s0 * inv, m1 = s1 * inv;
    const float r0 = rsqrtf(fmaxf(q0 * inv - m0*m0, 0.f) + 1e-5f);
    const float r1 = rsqrtf(fmaxf(q1 * inv - m1*m1, 0.f) + 1e-5f);
    const float4 w4 = ((const float4*)lnw)[tid];
    const float4 b4 = ((const float4*)lnb)[tid];
    const float4 k4 = ((const float4*)mkv)[tid];
    const float4 r4 = ((const float4*)mrv)[tid];
    const float cA[4] = {cur.x, cur.y, cur.z, cur.w};
    const float pA[4] = {prv.x, prv.y, prv.z, prv.w};
    const float wA[4] = {w4.x, w4.y, w4.z, w4.w};
    const float bA[4] = {b4.x, b4.y, b4.z, b4.w};
    const float kA[4] = {k4.x, k4.y, k4.z, k4.w};
    const float rA[4] = {r4.x, r4.y, r4.z, r4.w};
    ushort4 pk, pr;
    unsigned short* pkp = &pk.x; unsigned short* prp = &pr.x;
#pragma unroll
    for (int j = 0; j < 4; ++j) {
        float xa = (cA[j] - m0) * r0 * wA[j] + bA[j];
        float xs = (l > 0) ? ((pA[j] - m1) * r1 * wA[j] + bA[j]) : 0.f;
        pkp[j] = f2bf(xa * kA[j] + xs * (1.f - kA[j]));
        prp[j] = f2bf(xa * rA[j] + xs * (1.f - rA[j]));
    }
    const size_t oi = (size_t)row * (DDIM/4) + tid;
    ((ushort4*)ok)[oi]  = pk;
    ((ushort4*)orr)[oi] = pr;
}

// ---------------- WKV chunk-parallel scan ----------------
__global__ __launch_bounds__(256) void wkv_phase1(
    const __bf16* __restrict__ kin, const __bf16* __restrict__ vin,
    const float* __restrict__ td,
    float* __restrict__ sa, float* __restrict__ sb, float* __restrict__ sp)
{
    const int idx = blockIdx.x * 256 + threadIdx.x;
    const int d  = idx & (DDIM - 1);
    const int bc = idx >> 10;
    const int b  = bc & (BSZ - 1);
    const int c  = bc >> 3;
    const float w = -__expf(td[d]);
    const size_t base = ((size_t)b * LSEQ + (size_t)c * CLEN) * DDIM + d;
    float a = 0.f, bbv = 0.f, p = -1e38f;
    for (int t = 0; t < CLEN; ++t) {
        const size_t off = base + (size_t)t * DDIM;
        const float kt = (float)kin[off];
        const float vt = (float)vin[off];
        const float ww2 = p + w;
        const float q2  = fmaxf(ww2, kt);
        const float e1  = __expf(ww2 - q2);
        const float e2  = __expf(kt - q2);
        a   = e1 * a   + e2 * vt;
        bbv = e1 * bbv + e2;
        p   = q2;
    }
    sa[idx] = a; sb[idx] = bbv; sp[idx] = p;
}

__global__ __launch_bounds__(256) void wkv_phase2(
    const __bf16* __restrict__ kin, const __bf16* __restrict__ vin,
    const __bf16* __restrict__ srin,
    const float* __restrict__ td, const float* __restrict__ tf,
    const float* __restrict__ sa, const float* __restrict__ sb,
    const float* __restrict__ sp,
    __bf16* __restrict__ outp)
{
    const int idx = blockIdx.x * 256 + threadIdx.x;
    const int d  = idx & (DDIM - 1);
    const int bc = idx >> 10;
    const int b  = bc & (BSZ - 1);
    const int c  = bc >> 3;
    const float w = -__expf(td[d]);
    const float u = tf[d];
    const float nw = (float)CLEN * w;

    float a = 0.f, bbv = 0.f, p = -1e38f;
    for (int j = 0; j < c; ++j) {
        const int sidx = ((j * BSZ + b) << 10) + d;
        const float aj = sa[sidx], bj = sb[sidx], pj = sp[sidx];
        const float ps = p + nw;
        const float pn = fmaxf(ps, pj);
        const float e1 = __expf(ps - pn);
        const float e2 = __expf(pj - pn);
        a   = e1 * a   + e2 * aj;
        bbv = e1 * bbv + e2 * bj;
        p   = pn;
    }

    const size_t base = ((size_t)b * LSEQ + (size_t)c * CLEN) * DDIM + d;
    for (int t = 0; t < CLEN; ++t) {
        const size_t off = base + (size_t)t * DDIM;
        const float kt = (float)kin[off];
        const float vt = (float)vin[off];
        const float sr = (float)srin[off];
        const float ww = u + kt;
        const float q  = fmaxf(p, ww);
        const float e1 = __expf(p - q);
        const float e2 = __expf(ww - q);
        const float o  = (e1 * a + e2 * vt) / (e1 * bbv + e2);
        outp[off] = (__bf16)(sr * o);
        const float ww2 = p + w;
        const float q2  = fmaxf(ww2, kt);
        const float e1b = __expf(ww2 - q2);
        const float e2b = __expf(kt - q2);
        a   = e1b * a   + e2b * vt;
        bbv = e1b * bbv + e2b;
        p   = q2;
    }
}

// ---------------- 256x256 pipelined bf16 GEMM: C[M,N] = A[M,K] @ B[N,K]^T ----------------
// 8 waves (2x4), BK=32, 4-buffer LDS ring (4x32KiB), prefetch distance 2,
// counted vmcnt (never 0 in main loop), T2 swizzle, T5 setprio, T1 XCD remap.
// EPI: 1 sigmoid->bf16; 2 relu^2->bf16; 3 auxF+acc->f32; 4 auxF+auxH*acc->f32; 5 bf16
template<int EPI>
__global__ __launch_bounds__(512, 2)
void gemm8(const __bf16* __restrict__ A, const __bf16* __restrict__ Bw,
           float* outF, __bf16* outH,
           const float* auxF, const __bf16* __restrict__ auxH,
           int N, int K, int gy)
{
    __shared__ __align__(16) char smem[131072];   // 4 bufs x (16KiB A + 16KiB B)
    const int tid  = threadIdx.x;
    const int lane = tid & 63;
    const int wid  = tid >> 6;
    const int wr = wid >> 2, wc = wid & 3;

    // T1: XCD-bijective remap (nwg % 8 == 0 guaranteed), gy-major for A-panel L2 reuse
    const int nwg = gridDim.x;
    const int f = blockIdx.x;
    const int g = (f & 7) * (nwg >> 3) + (f >> 3);
    const int tx = g / gy;
    const int ty = g - tx * gy;
    const size_t row0 = (size_t)tx * 256;
    const size_t col0 = (size_t)ty * 256;

    // staging: dest (linear) byte in 16KiB region = q*8192 + tid*16.
    // T2 involution swizzle: image_off = L ^ (((L>>7)&3)<<4)  (bits 4-5 only)
    auto stage = [&](int buf, int k0, int isB, int q) {
        const int row  = q * 128 + (tid >> 2);
        const int slot = (tid & 3) ^ ((row >> 1) & 3);
        const __bf16* gp = (isB ? Bw + (col0 + row) * (size_t)K
                                : A  + (row0 + row) * (size_t)K) + k0 + slot * 8;
        char* lp = smem + buf * 32768 + isB * 16384 + q * 8192 + wid * 1024;
        gload16(gp, lp);
    };
    // fragment reads (swizzled): image byte = row*64 + (lane>>4)*16
    auto rdA = [&](int buf, int m) -> u32x4 {
        const int row  = wr * 128 + m * 16 + (lane & 15);
        const int slot = (lane >> 4) ^ ((row >> 1) & 3);
        return *(const u32x4*)(smem + buf * 32768 + row * 64 + slot * 16);
    };
    auto rdB = [&](int buf, int n) -> u32x4 {
        const int row  = wc * 64 + n * 16 + (lane & 15);
        const int slot = (lane >> 4) ^ ((row >> 1) & 3);
        return *(const u32x4*)(smem + buf * 32768 + 16384 + row * 64 + slot * 16);
    };

    f32x4 acc[8][4] = {};
    const int ns = K / 32;

    // prologue: steps 0 -> buf0, 1 -> buf1  (4 issues each)
    stage(0, 0, 0, 0); stage(0, 0, 0, 1); stage(0, 0, 1, 0); stage(0, 0, 1, 1);
    stage(1, 32, 0, 0); stage(1, 32, 0, 1); stage(1, 32, 1, 0); stage(1, 32, 1, 1);

    for (int t = 0; t < ns; ++t) {
        const int cb = t & 3;
        // own loads for step t retired; step t+1's 4 issues may remain in flight
        if (t < ns - 1) asm volatile("s_waitcnt vmcnt(4)" ::: "memory");
        else            asm volatile("s_waitcnt vmcnt(0)" ::: "memory");
        __builtin_amdgcn_s_barrier();

        const int pf = t + 2;
        const int pb = pf & 3;
        const int pk = pf * 32;

        // ---- phase A: frags + A-prefetch + MFMA m0-3 ----
        u32x4 bfr[4];
#pragma unroll
        for (int n = 0; n < 4; ++n) bfr[n] = rdB(cb, n);
        u32x4 afr[4];
#pragma unroll
        for (int m = 0; m < 4; ++m) afr[m] = rdA(cb, m);
        if (pf < ns) { stage(pb, pk, 0, 0); stage(pb, pk, 0, 1); }
        __builtin_amdgcn_s_setprio(1);
#pragma unroll
        for (int m = 0; m < 4; ++m)
#pragma unroll
            for (int n = 0; n < 4; ++n)
                mfma_bf16(acc[m][n], afr[m], bfr[n]);
        __builtin_amdgcn_s_setprio(0);
        __builtin_amdgcn_s_barrier();

        // ---- phase B: frags + B-prefetch + MFMA m4-7 ----
#pragma unroll
        for (int m = 0; m < 4; ++m) afr[m] = rdA(cb, m + 4);
        if (pf < ns) { stage(pb, pk, 1, 0); stage(pb, pk, 1, 1); }
        __builtin_amdgcn_s_setprio(1);
#pragma unroll
        for (int m = 0; m < 4; ++m)
#pragma unroll
            for (int n = 0; n < 4; ++n)
                mfma_bf16(acc[m + 4][n], afr[m], bfr[n]);
        __builtin_amdgcn_s_setprio(0);
    }
    asm volatile("s_nop 7\n\ts_nop 7\n\ts_nop 3");

    // C/D layout: col = lane&15, row = 4*(lane>>4) + reg  [verified r2/r3]
    const size_t obr = row0 + wr * 128 + ((lane >> 4) << 2);
    const size_t obc = col0 + wc * 64 + (lane & 15);
#pragma unroll
    for (int m = 0; m < 8; ++m) {
#pragma unroll
        for (int n = 0; n < 4; ++n) {
#pragma unroll
            for (int j = 0; j < 4; ++j) {
                const size_t idx = (obr + m * 16 + j) * (size_t)N + obc + n * 16;
                const float v = acc[m][n][j];
                if constexpr (EPI == 1) {
                    outH[idx] = (__bf16)(1.f / (1.f + __expf(-v)));
                } else if constexpr (EPI == 2) {
                    const float t2 = fmaxf(v, 0.f);
                    outH[idx] = (__bf16)(t2 * t2);
                } else if constexpr (EPI == 3) {
                    outF[idx] = auxF[idx] + v;
                } else if constexpr (EPI == 4) {
                    outF[idx] = auxF[idx] + (float)auxH[idx] * v;
                } else {
                    outH[idx] = (__bf16)v;
                }
            }
        }
    }
}

extern "C" void kernel_launch(void* const* d_in, const int* in_sizes, int n_in,
                              void* d_out, int out_size, void* d_ws, size_t ws_size,
                              hipStream_t stream)
{
    const float* x    = (const float*)d_in[0];
    const float* lnaw = (const float*)d_in[1];
    const float* lnab = (const float*)d_in[2];
    const float* lnfw = (const float*)d_in[3];
    const float* lnfb = (const float*)d_in[4];
    const float* tdec = (const float*)d_in[5];
    const float* tfir = (const float*)d_in[6];
    const float* amk  = (const float*)d_in[7];
    const float* amv  = (const float*)d_in[8];
    const float* amr  = (const float*)d_in[9];
    const float* aWk  = (const float*)d_in[10];
    const float* aWv  = (const float*)d_in[11];
    const float* aWr  = (const float*)d_in[12];
    const float* aWo  = (const float*)d_in[13];
    const float* fmk  = (const float*)d_in[14];
    const float* fmr  = (const float*)d_in[15];
    const float* fWk  = (const float*)d_in[16];
    const float* fWv  = (const float*)d_in[17];
    const float* fWr  = (const float*)d_in[18];
    float* out = (float*)d_out;

    char* ws = (char*)d_ws;
    const size_t MiB = 1ull << 20;
    __bf16* Wk_h  = (__bf16*)ws;
    __bf16* Wv_h  = Wk_h + (1ull << 20);
    __bf16* Wr_h  = Wk_h + (2ull << 20);
    __bf16* Wo_h  = Wk_h + (3ull << 20);
    __bf16* fWk_h = Wk_h + (4ull << 20);
    __bf16* fWv_h = Wk_h + (8ull << 20);
    __bf16* fWr_h = Wk_h + (12ull << 20);
    // activations — peak ws extent = 221 MiB
    __bf16* xk = (__bf16*)(ws + 26 * MiB);
    __bf16* xv = (__bf16*)(ws + 58 * MiB);
    __bf16* xr = (__bf16*)(ws + 90 * MiB);
    __bf16* kb = (__bf16*)(ws + 122 * MiB);
    __bf16* vb = (__bf16*)(ws + 154 * MiB);
    __bf16* sr = (__bf16*)(ws + 186 * MiB);
    float* st_a = (float*)(ws + 218 * MiB);
    float* st_b = (float*)(ws + 219 * MiB);
    float* st_p = (float*)(ws + 220 * MiB);
    __bf16* atta = xk;
    __bf16* kx   = xv;
    __bf16* rx   = xr;
    __bf16* sb   = xk;
    __bf16* hb   = (__bf16*)(ws + 90 * MiB);

    // 1. weights -> bf16
    cvt_bf16<<<1024, 256, 0, stream>>>(aWk, Wk_h,  1 << 18);
    cvt_bf16<<<1024, 256, 0, stream>>>(aWv, Wv_h,  1 << 18);
    cvt_bf16<<<1024, 256, 0, stream>>>(aWr, Wr_h,  1 << 18);
    cvt_bf16<<<1024, 256, 0, stream>>>(aWo, Wo_h,  1 << 18);
    cvt_bf16<<<4096, 256, 0, stream>>>(fWk, fWk_h, 1 << 20);
    cvt_bf16<<<4096, 256, 0, stream>>>(fWv, fWv_h, 1 << 20);
    cvt_bf16<<<1024, 256, 0, stream>>>(fWr, fWr_h, 1 << 18);

    // 2. attention LN + shift + mix
    ln_mix3<<<MROWS, 256, 0, stream>>>(x, lnaw, lnab, amk, amv, amr, xk, xv, xr);

    // 3. k, v (bf16), sigmoid(r)
    const int gD = (MROWS / 256) * (DDIM / 256);   // 256 blocks
    const int gF = (MROWS / 256) * (FDIM / 256);   // 1024 blocks
    gemm8<5><<<gD, 512, 0, stream>>>(xk, Wk_h, nullptr, kb, nullptr, nullptr, DDIM, DDIM, DDIM/256);
    gemm8<5><<<gD, 512, 0, stream>>>(xv, Wv_h, nullptr, vb, nullptr, nullptr, DDIM, DDIM, DDIM/256);
    gemm8<1><<<gD, 512, 0, stream>>>(xr, Wr_h, nullptr, sr, nullptr, nullptr, DDIM, DDIM, DDIM/256);

    // 4. WKV chunk-parallel scan -> sigmoid(r) * wkv (bf16), into xk region
    const int nthreads = BSZ * DDIM * NCHUNK;
    wkv_phase1<<<nthreads / 256, 256, 0, stream>>>(kb, vb, tdec, st_a, st_b, st_p);
    wkv_phase2<<<nthreads / 256, 256, 0, stream>>>(kb, vb, sr, tdec, tfir,
                                                   st_a, st_b, st_p, atta);

    // 5. att output projection + residual -> d_out (= x_new)
    gemm8<3><<<gD, 512, 0, stream>>>(atta, Wo_h, out, nullptr, x, nullptr, DDIM, DDIM, DDIM/256);

    // 6. FFN LN + shift + mix (reads d_out)
    ln_mix2<<<MROWS, 256, 0, stream>>>(out, lnfw, lnfb, fmk, fmr, kx, rx);

    // 7a. s = sigmoid(rx @ fWr^T)  (before h so rx region can be reused)
    gemm8<1><<<gD, 512, 0, stream>>>(rx, fWr_h, nullptr, sb, nullptr, nullptr, DDIM, DDIM, DDIM/256);

    // 7b. h = relu(kx @ fWk^T)^2
    gemm8<2><<<gF, 512, 0, stream>>>(kx, fWk_h, nullptr, hb, nullptr, nullptr, FDIM, DDIM, FDIM/256);

    // 8. d_out = x_new + s * (h @ fWv^T)
    gemm8<4><<<gD, 512, 0, stream>>>(hb, fWv_h, out, nullptr, out, sb, DDIM, FDIM, DDIM/256);
}

// Round 5
// 719.365 us; speedup vs baseline: 1.7006x; 1.0250x over previous
//
#include <hip/hip_runtime.h>
#include <stdint.h>

// Problem dims (fixed by harness)
#define DDIM 1024
#define LSEQ 2048
#define BSZ  8
#define FDIM 4096
#define MROWS (BSZ*LSEQ)   // 16384
#define NCHUNK 32
#define CLEN  (LSEQ/NCHUNK)   // 64

typedef float        f32x4  __attribute__((ext_vector_type(4)));
typedef unsigned int u32x4  __attribute__((ext_vector_type(4)));

using gas_void = const __attribute__((address_space(1))) void;
using las_void = __attribute__((address_space(3))) void;

__device__ __forceinline__ void gload16(const void* g, void* l) {
    // async global->LDS, 16B per lane; LDS dest = wave-uniform base + lane*16
    __builtin_amdgcn_global_load_lds((gas_void*)g, (las_void*)l, 16, 0, 0);
}

__device__ __forceinline__ void mfma_bf16(f32x4& d, u32x4 a, u32x4 b) {
    asm("v_mfma_f32_16x16x32_bf16 %0, %1, %2, %0" : "+v"(d) : "v"(a), "v"(b));
}

__device__ __forceinline__ unsigned short f2bf(float f) {
    __bf16 h = (__bf16)f;
    return __builtin_bit_cast(unsigned short, h);
}

// ---------------- fused weight fp32 -> bf16 (all 7 matrices, 1 launch) ----------------
struct CvtArgs {
    const float* s[7];
    __bf16*      d[7];
    int          cum[8];   // cumulative float4 counts
};

__global__ __launch_bounds__(256) void cvt_all(CvtArgs a)
{
    const int i = blockIdx.x * 256 + threadIdx.x;
    if (i >= a.cum[7]) return;
    int seg = 0;
#pragma unroll 6
    while (i >= a.cum[seg + 1]) ++seg;
    const int off = i - a.cum[seg];
    float4 f = ((const float4*)a.s[seg])[off];
    ushort4 o;
    o.x = f2bf(f.x); o.y = f2bf(f.y); o.z = f2bf(f.z); o.w = f2bf(f.w);
    ((ushort4*)a.d[seg])[off] = o;
}

// ---------------- block reduce (4 scalars over 256 threads) ----------------
__device__ __forceinline__ void blk_reduce4(float& a, float& b, float& c, float& d) {
#pragma unroll
    for (int off = 32; off >= 1; off >>= 1) {
        a += __shfl_xor(a, off, 64);
        b += __shfl_xor(b, off, 64);
        c += __shfl_xor(c, off, 64);
        d += __shfl_xor(d, off, 64);
    }
    __shared__ float sm[4][4];
    const int tid = threadIdx.x;
    if ((tid & 63) == 0) {
        sm[tid >> 6][0] = a; sm[tid >> 6][1] = b;
        sm[tid >> 6][2] = c; sm[tid >> 6][3] = d;
    }
    __syncthreads();
    a = sm[0][0] + sm[1][0] + sm[2][0] + sm[3][0];
    b = sm[0][1] + sm[1][1] + sm[2][1] + sm[3][1];
    c = sm[0][2] + sm[1][2] + sm[2][2] + sm[3][2];
    d = sm[0][3] + sm[1][3] + sm[2][3] + sm[3][3];
}

// ---------------- LN + time_shift + mix (attention: 3 outputs) ----------------
__global__ __launch_bounds__(256) void ln_mix3(
    const float* __restrict__ xin, const float* __restrict__ lnw, const float* __restrict__ lnb,
    const float* __restrict__ mkv, const float* __restrict__ mvv, const float* __restrict__ mrv,
    __bf16* __restrict__ ok, __bf16* __restrict__ ov, __bf16* __restrict__ orr)
{
    const int row = blockIdx.x;          // b*L + l
    const int l   = row & (LSEQ - 1);
    const int tid = threadIdx.x;
    const size_t rbase = (size_t)row * DDIM;
    const float4 cur = ((const float4*)(xin + rbase))[tid];
    float4 prv = make_float4(0.f, 0.f, 0.f, 0.f);
    if (l > 0) prv = ((const float4*)(xin + rbase - DDIM))[tid];
    float s0 = cur.x + cur.y + cur.z + cur.w;
    float q0 = cur.x*cur.x + cur.y*cur.y + cur.z*cur.z + cur.w*cur.w;
    float s1 = prv.x + prv.y + prv.z + prv.w;
    float q1 = prv.x*prv.x + prv.y*prv.y + prv.z*prv.z + prv.w*prv.w;
    blk_reduce4(s0, q0, s1, q1);
    const float inv = 1.f / (float)DDIM;
    const float m0 = s0 * inv, m1 = s1 * inv;
    const float r0 = rsqrtf(fmaxf(q0 * inv - m0*m0, 0.f) + 1e-5f);
    const float r1 = rsqrtf(fmaxf(q1 * inv - m1*m1, 0.f) + 1e-5f);
    const float4 w4 = ((const float4*)lnw)[tid];
    const float4 b4 = ((const float4*)lnb)[tid];
    const float4 k4 = ((const float4*)mkv)[tid];
    const float4 v4 = ((const float4*)mvv)[tid];
    const float4 r4 = ((const float4*)mrv)[tid];
    const float cA[4] = {cur.x, cur.y, cur.z, cur.w};
    const float pA[4] = {prv.x, prv.y, prv.z, prv.w};
    const float wA[4] = {w4.x, w4.y, w4.z, w4.w};
    const float bA[4] = {b4.x, b4.y, b4.z, b4.w};
    const float kA[4] = {k4.x, k4.y, k4.z, k4.w};
    const float vA[4] = {v4.x, v4.y, v4.z, v4.w};
    const float rA[4] = {r4.x, r4.y, r4.z, r4.w};
    ushort4 pk, pv, pr;
    unsigned short* pkp = &pk.x; unsigned short* pvp = &pv.x; unsigned short* prp = &pr.x;
#pragma unroll
    for (int j = 0; j < 4; ++j) {
        float xa = (cA[j] - m0) * r0 * wA[j] + bA[j];
        float xs = (l > 0) ? ((pA[j] - m1) * r1 * wA[j] + bA[j]) : 0.f;
        pkp[j] = f2bf(xa * kA[j] + xs * (1.f - kA[j]));
        pvp[j] = f2bf(xa * vA[j] + xs * (1.f - vA[j]));
        prp[j] = f2bf(xa * rA[j] + xs * (1.f - rA[j]));
    }
    const size_t oi = (size_t)row * (DDIM/4) + tid;
    ((ushort4*)ok)[oi]  = pk;
    ((ushort4*)ov)[oi]  = pv;
    ((ushort4*)orr)[oi] = pr;
}

// ---------------- LN + time_shift + mix (FFN: 2 outputs) ----------------
__global__ __launch_bounds__(256) void ln_mix2(
    const float* __restrict__ xin, const float* __restrict__ lnw, const float* __restrict__ lnb,
    const float* __restrict__ mkv, const float* __restrict__ mrv,
    __bf16* __restrict__ ok, __bf16* __restrict__ orr)
{
    const int row = blockIdx.x;
    const int l   = row & (LSEQ - 1);
    const int tid = threadIdx.x;
    const size_t rbase = (size_t)row * DDIM;
    const float4 cur = ((const float4*)(xin + rbase))[tid];
    float4 prv = make_float4(0.f, 0.f, 0.f, 0.f);
    if (l > 0) prv = ((const float4*)(xin + rbase - DDIM))[tid];
    float s0 = cur.x + cur.y + cur.z + cur.w;
    float q0 = cur.x*cur.x + cur.y*cur.y + cur.z*cur.z + cur.w*cur.w;
    float s1 = prv.x + prv.y + prv.z + prv.w;
    float q1 = prv.x*prv.x + prv.y*prv.y + prv.z*prv.z + prv.w*prv.w;
    blk_reduce4(s0, q0, s1, q1);
    const float inv = 1.f / (float)DDIM;
    const float m0 = s0 * inv, m1 = s1 * inv;
    const float r0 = rsqrtf(fmaxf(q0 * inv - m0*m0, 0.f) + 1e-5f);
    const float r1 = rsqrtf(fmaxf(q1 * inv - m1*m1, 0.f) + 1e-5f);
    const float4 w4 = ((const float4*)lnw)[tid];
    const float4 b4 = ((const float4*)lnb)[tid];
    const float4 k4 = ((const float4*)mkv)[tid];
    const float4 r4 = ((const float4*)mrv)[tid];
    const float cA[4] = {cur.x, cur.y, cur.z, cur.w};
    const float pA[4] = {prv.x, prv.y, prv.z, prv.w};
    const float wA[4] = {w4.x, w4.y, w4.z, w4.w};
    const float bA[4] = {b4.x, b4.y, b4.z, b4.w};
    const float kA[4] = {k4.x, k4.y, k4.z, k4.w};
    const float rA[4] = {r4.x, r4.y, r4.z, r4.w};
    ushort4 pk, pr;
    unsigned short* pkp = &pk.x; unsigned short* prp = &pr.x;
#pragma unroll
    for (int j = 0; j < 4; ++j) {
        float xa = (cA[j] - m0) * r0 * wA[j] + bA[j];
        float xs = (l > 0) ? ((pA[j] - m1) * r1 * wA[j] + bA[j]) : 0.f;
        pkp[j] = f2bf(xa * kA[j] + xs * (1.f - kA[j]));
        prp[j] = f2bf(xa * rA[j] + xs * (1.f - rA[j]));
    }
    const size_t oi = (size_t)row * (DDIM/4) + tid;
    ((ushort4*)ok)[oi]  = pk;
    ((ushort4*)orr)[oi] = pr;
}

// ---------------- WKV chunk-parallel scan ----------------
__global__ __launch_bounds__(256) void wkv_phase1(
    const __bf16* __restrict__ kin, const __bf16* __restrict__ vin,
    const float* __restrict__ td,
    float* __restrict__ sa, float* __restrict__ sb, float* __restrict__ sp)
{
    const int idx = blockIdx.x * 256 + threadIdx.x;
    const int d  = idx & (DDIM - 1);
    const int bc = idx >> 10;
    const int b  = bc & (BSZ - 1);
    const int c  = bc >> 3;
    const float w = -__expf(td[d]);
    const size_t base = ((size_t)b * LSEQ + (size_t)c * CLEN) * DDIM + d;
    float a = 0.f, bbv = 0.f, p = -1e38f;
    for (int t = 0; t < CLEN; ++t) {
        const size_t off = base + (size_t)t * DDIM;
        const float kt = (float)kin[off];
        const float vt = (float)vin[off];
        const float ww2 = p + w;
        const float q2  = fmaxf(ww2, kt);
        const float e1  = __expf(ww2 - q2);
        const float e2  = __expf(kt - q2);
        a   = e1 * a   + e2 * vt;
        bbv = e1 * bbv + e2;
        p   = q2;
    }
    sa[idx] = a; sb[idx] = bbv; sp[idx] = p;
}

__global__ __launch_bounds__(256) void wkv_phase2(
    const __bf16* __restrict__ kin, const __bf16* __restrict__ vin,
    const __bf16* __restrict__ srin,
    const float* __restrict__ td, const float* __restrict__ tf,
    const float* __restrict__ sa, const float* __restrict__ sb,
    const float* __restrict__ sp,
    __bf16* __restrict__ outp)
{
    const int idx = blockIdx.x * 256 + threadIdx.x;
    const int d  = idx & (DDIM - 1);
    const int bc = idx >> 10;
    const int b  = bc & (BSZ - 1);
    const int c  = bc >> 3;
    const float w = -__expf(td[d]);
    const float u = tf[d];
    const float nw = (float)CLEN * w;

    float a = 0.f, bbv = 0.f, p = -1e38f;
    for (int j = 0; j < c; ++j) {
        const int sidx = ((j * BSZ + b) << 10) + d;
        const float aj = sa[sidx], bj = sb[sidx], pj = sp[sidx];
        const float ps = p + nw;
        const float pn = fmaxf(ps, pj);
        const float e1 = __expf(ps - pn);
        const float e2 = __expf(pj - pn);
        a   = e1 * a   + e2 * aj;
        bbv = e1 * bbv + e2 * bj;
        p   = pn;
    }

    const size_t base = ((size_t)b * LSEQ + (size_t)c * CLEN) * DDIM + d;
    for (int t = 0; t < CLEN; ++t) {
        const size_t off = base + (size_t)t * DDIM;
        const float kt = (float)kin[off];
        const float vt = (float)vin[off];
        const float sr = (float)srin[off];
        const float ww = u + kt;
        const float q  = fmaxf(p, ww);
        const float e1 = __expf(p - q);
        const float e2 = __expf(ww - q);
        const float o  = (e1 * a + e2 * vt) / (e1 * bbv + e2);
        outp[off] = (__bf16)(sr * o);
        const float ww2 = p + w;
        const float q2  = fmaxf(ww2, kt);
        const float e1b = __expf(ww2 - q2);
        const float e2b = __expf(kt - q2);
        a   = e1b * a   + e2b * vt;
        bbv = e1b * bbv + e2b;
        p   = q2;
    }
}

// ---------------- 256x256 pipelined bf16 GEMM: C[M,N] = A[M,K] @ B[N,K]^T ----------------
// 8 waves (2x4), BK=32, 4-buffer LDS ring, prefetch distance 3, ONE barrier per step,
// counted vmcnt(8) (never 0 in main loop), T2 swizzle, T5 setprio, T1 XCD remap.
// EPI: 1 sigmoid->bf16; 2 relu^2->bf16; 3 auxF+acc->f32; 4 auxF+auxH*acc->f32; 5 bf16
template<int EPI>
__global__ __launch_bounds__(512, 2)
void gemm8(const __bf16* __restrict__ A, const __bf16* __restrict__ Bw,
           float* outF, __bf16* outH,
           const float* auxF, const __bf16* __restrict__ auxH,
           int N, int K, int gy)
{
    __shared__ __align__(16) char smem[131072];   // 4 bufs x (16KiB A + 16KiB B)
    const int tid  = threadIdx.x;
    const int lane = tid & 63;
    const int wid  = tid >> 6;
    const int wr = wid >> 2, wc = wid & 3;

    // T1: XCD-bijective remap (nwg % 8 == 0 guaranteed), gy-major for A-panel L2 reuse
    const int nwg = gridDim.x;
    const int f = blockIdx.x;
    const int g = (f & 7) * (nwg >> 3) + (f >> 3);
    const int tx = g / gy;
    const int ty = g - tx * gy;
    const size_t row0 = (size_t)tx * 256;
    const size_t col0 = (size_t)ty * 256;

    // staging: dest (linear) byte in 16KiB region = q*8192 + tid*16.
    // T2 involution swizzle on k-chunk slot: slot ^= (row>>1)&3
    auto stage = [&](int buf, int k0, int isB, int q) {
        const int row  = q * 128 + (tid >> 2);
        const int slot = (tid & 3) ^ ((row >> 1) & 3);
        const __bf16* gp = (isB ? Bw + (col0 + row) * (size_t)K
                                : A  + (row0 + row) * (size_t)K) + k0 + slot * 8;
        char* lp = smem + buf * 32768 + isB * 16384 + q * 8192 + wid * 1024;
        gload16(gp, lp);
    };
    // fragment reads (swizzled)
    auto rdA = [&](int buf, int m) -> u32x4 {
        const int row  = wr * 128 + m * 16 + (lane & 15);
        const int slot = (lane >> 4) ^ ((row >> 1) & 3);
        return *(const u32x4*)(smem + buf * 32768 + row * 64 + slot * 16);
    };
    auto rdB = [&](int buf, int n) -> u32x4 {
        const int row  = wc * 64 + n * 16 + (lane & 15);
        const int slot = (lane >> 4) ^ ((row >> 1) & 3);
        return *(const u32x4*)(smem + buf * 32768 + 16384 + row * 64 + slot * 16);
    };

    f32x4 acc[8][4] = {};
    const int ns = K / 32;   // >= 32 for all our shapes

    // prologue: stage steps 0,1,2 (4 issues each; 12 in flight)
    stage(0,  0, 0, 0); stage(0,  0, 0, 1); stage(0,  0, 1, 0); stage(0,  0, 1, 1);
    stage(1, 32, 0, 0); stage(1, 32, 0, 1); stage(1, 32, 1, 0); stage(1, 32, 1, 1);
    stage(2, 64, 0, 0); stage(2, 64, 0, 1); stage(2, 64, 1, 0); stage(2, 64, 1, 1);

    for (int t = 0; t < ns; ++t) {
        const int cb = t & 3;
        // retire own step-t loads; keep up to 8 (steps t+1, t+2) in flight
        if (t < ns - 2)       asm volatile("s_waitcnt vmcnt(8)" ::: "memory");
        else if (t == ns - 2) asm volatile("s_waitcnt vmcnt(4)" ::: "memory");
        else                  asm volatile("s_waitcnt vmcnt(0)" ::: "memory");
        __builtin_amdgcn_s_barrier();

        const int pf = t + 3;
        const int pb = pf & 3;
        const int pk = pf * 32;

        // ---- frags (phase A) + A-prefetch + MFMA m0-3 ----
        u32x4 bfr[4];
#pragma unroll
        for (int n = 0; n < 4; ++n) bfr[n] = rdB(cb, n);
        u32x4 afr[4];
#pragma unroll
        for (int m = 0; m < 4; ++m) afr[m] = rdA(cb, m);
        if (pf < ns) { stage(pb, pk, 0, 0); stage(pb, pk, 0, 1); }
        __builtin_amdgcn_s_setprio(1);
#pragma unroll
        for (int m = 0; m < 4; ++m)
#pragma unroll
            for (int n = 0; n < 4; ++n)
                mfma_bf16(acc[m][n], afr[m], bfr[n]);
        __builtin_amdgcn_s_setprio(0);

        // ---- frags (phase B) + B-prefetch + MFMA m4-7 (no mid barrier) ----
        u32x4 afr2[4];
#pragma unroll
        for (int m = 0; m < 4; ++m) afr2[m] = rdA(cb, m + 4);
        if (pf < ns) { stage(pb, pk, 1, 0); stage(pb, pk, 1, 1); }
        __builtin_amdgcn_s_setprio(1);
#pragma unroll
        for (int m = 0; m < 4; ++m)
#pragma unroll
            for (int n = 0; n < 4; ++n)
                mfma_bf16(acc[m + 4][n], afr2[m], bfr[n]);
        __builtin_amdgcn_s_setprio(0);
    }
    asm volatile("s_nop 7\n\ts_nop 7\n\ts_nop 3");

    // C/D layout: col = lane&15, row = 4*(lane>>4) + reg  [verified r2-r4]
    const size_t obr = row0 + wr * 128 + ((lane >> 4) << 2);
    const size_t obc = col0 + wc * 64 + (lane & 15);
#pragma unroll
    for (int m = 0; m < 8; ++m) {
#pragma unroll
        for (int n = 0; n < 4; ++n) {
#pragma unroll
            for (int j = 0; j < 4; ++j) {
                const size_t idx = (obr + m * 16 + j) * (size_t)N + obc + n * 16;
                const float v = acc[m][n][j];
                if constexpr (EPI == 1) {
                    outH[idx] = (__bf16)(1.f / (1.f + __expf(-v)));
                } else if constexpr (EPI == 2) {
                    const float t2 = fmaxf(v, 0.f);
                    outH[idx] = (__bf16)(t2 * t2);
                } else if constexpr (EPI == 3) {
                    outF[idx] = auxF[idx] + v;
                } else if constexpr (EPI == 4) {
                    outF[idx] = auxF[idx] + (float)auxH[idx] * v;
                } else {
                    outH[idx] = (__bf16)v;
                }
            }
        }
    }
}

extern "C" void kernel_launch(void* const* d_in, const int* in_sizes, int n_in,
                              void* d_out, int out_size, void* d_ws, size_t ws_size,
                              hipStream_t stream)
{
    const float* x    = (const float*)d_in[0];
    const float* lnaw = (const float*)d_in[1];
    const float* lnab = (const float*)d_in[2];
    const float* lnfw = (const float*)d_in[3];
    const float* lnfb = (const float*)d_in[4];
    const float* tdec = (const float*)d_in[5];
    const float* tfir = (const float*)d_in[6];
    const float* amk  = (const float*)d_in[7];
    const float* amv  = (const float*)d_in[8];
    const float* amr  = (const float*)d_in[9];
    const float* aWk  = (const float*)d_in[10];
    const float* aWv  = (const float*)d_in[11];
    const float* aWr  = (const float*)d_in[12];
    const float* aWo  = (const float*)d_in[13];
    const float* fmk  = (const float*)d_in[14];
    const float* fmr  = (const float*)d_in[15];
    const float* fWk  = (const float*)d_in[16];
    const float* fWv  = (const float*)d_in[17];
    const float* fWr  = (const float*)d_in[18];
    float* out = (float*)d_out;

    char* ws = (char*)d_ws;
    const size_t MiB = 1ull << 20;
    __bf16* Wk_h  = (__bf16*)ws;
    __bf16* Wv_h  = Wk_h + (1ull << 20);
    __bf16* Wr_h  = Wk_h + (2ull << 20);
    __bf16* Wo_h  = Wk_h + (3ull << 20);
    __bf16* fWk_h = Wk_h + (4ull << 20);
    __bf16* fWv_h = Wk_h + (8ull << 20);
    __bf16* fWr_h = Wk_h + (12ull << 20);
    // activations — peak ws extent = 221 MiB
    __bf16* xk = (__bf16*)(ws + 26 * MiB);
    __bf16* xv = (__bf16*)(ws + 58 * MiB);
    __bf16* xr = (__bf16*)(ws + 90 * MiB);
    __bf16* kb = (__bf16*)(ws + 122 * MiB);
    __bf16* vb = (__bf16*)(ws + 154 * MiB);
    __bf16* sr = (__bf16*)(ws + 186 * MiB);
    float* st_a = (float*)(ws + 218 * MiB);
    float* st_b = (float*)(ws + 219 * MiB);
    float* st_p = (float*)(ws + 220 * MiB);
    __bf16* atta = xk;
    __bf16* kx   = xv;
    __bf16* rx   = xr;
    __bf16* sb   = xk;
    __bf16* hb   = (__bf16*)(ws + 90 * MiB);

    // 1. weights -> bf16 (single fused launch)
    CvtArgs ca;
    ca.s[0] = aWk;  ca.d[0] = Wk_h;
    ca.s[1] = aWv;  ca.d[1] = Wv_h;
    ca.s[2] = aWr;  ca.d[2] = Wr_h;
    ca.s[3] = aWo;  ca.d[3] = Wo_h;
    ca.s[4] = fWk;  ca.d[4] = fWk_h;
    ca.s[5] = fWv;  ca.d[5] = fWv_h;
    ca.s[6] = fWr;  ca.d[6] = fWr_h;
    {
        const int sz[7] = {1<<18, 1<<18, 1<<18, 1<<18, 1<<20, 1<<20, 1<<18};
        int c = 0;
        for (int i = 0; i < 7; ++i) { ca.cum[i] = c; c += sz[i]; }
        ca.cum[7] = c;   // 3407872 float4s
    }
    cvt_all<<<(ca.cum[7] + 255) / 256, 256, 0, stream>>>(ca);

    // 2. attention LN + shift + mix
    ln_mix3<<<MROWS, 256, 0, stream>>>(x, lnaw, lnab, amk, amv, amr, xk, xv, xr);

    // 3. k, v (bf16), sigmoid(r)
    const int gD = (MROWS / 256) * (DDIM / 256);   // 256 blocks
    const int gF = (MROWS / 256) * (FDIM / 256);   // 1024 blocks
    gemm8<5><<<gD, 512, 0, stream>>>(xk, Wk_h, nullptr, kb, nullptr, nullptr, DDIM, DDIM, DDIM/256);
    gemm8<5><<<gD, 512, 0, stream>>>(xv, Wv_h, nullptr, vb, nullptr, nullptr, DDIM, DDIM, DDIM/256);
    gemm8<1><<<gD, 512, 0, stream>>>(xr, Wr_h, nullptr, sr, nullptr, nullptr, DDIM, DDIM, DDIM/256);

    // 4. WKV chunk-parallel scan -> sigmoid(r) * wkv (bf16), into xk region
    const int nthreads = BSZ * DDIM * NCHUNK;
    wkv_phase1<<<nthreads / 256, 256, 0, stream>>>(kb, vb, tdec, st_a, st_b, st_p);
    wkv_phase2<<<nthreads / 256, 256, 0, stream>>>(kb, vb, sr, tdec, tfir,
                                                   st_a, st_b, st_p, atta);

    // 5. att output projection + residual -> d_out (= x_new)
    gemm8<3><<<gD, 512, 0, stream>>>(atta, Wo_h, out, nullptr, x, nullptr, DDIM, DDIM, DDIM/256);

    // 6. FFN LN + shift + mix (reads d_out)
    ln_mix2<<<MROWS, 256, 0, stream>>>(out, lnfw, lnfb, fmk, fmr, kx, rx);

    // 7a. s = sigmoid(rx @ fWr^T)  (before h so rx region can be reused)
    gemm8<1><<<gD, 512, 0, stream>>>(rx, fWr_h, nullptr, sb, nullptr, nullptr, DDIM, DDIM, DDIM/256);

    // 7b. h = relu(kx @ fWk^T)^2
    gemm8<2><<<gF, 512, 0, stream>>>(kx, fWk_h, nullptr, hb, nullptr, nullptr, FDIM, DDIM, FDIM/256);

    // 8. d_out = x_new + s * (h @ fWv^T)
    gemm8<4><<<gD, 512, 0, stream>>>(hb, fWv_h, out, nullptr, out, sb, DDIM, FDIM, DDIM/256);
}